// Round 2
// baseline (3906.148 us; speedup 1.0000x reference)
//
#include <hip/hip_runtime.h>

#define HID 51
#define TLEN 1024
#define NTH 448          // 7 waves; gate lanes = 8*51 = 408

__device__ __forceinline__ float frcp(float v) { return __builtin_amdgcn_rcpf(v); }
__device__ __forceinline__ float sigm(float v) { return frcp(1.0f + __expf(-v)); }

__global__ __launch_bounds__(NTH, 4)
void lstm2_kernel(const float* __restrict__ x,
                  const float* __restrict__ W_ih0, const float* __restrict__ W_hh0,
                  const float* __restrict__ b_ih0, const float* __restrict__ b_hh0,
                  const float* __restrict__ W_ih1, const float* __restrict__ W_hh1,
                  const float* __restrict__ b_ih1, const float* __restrict__ b_hh1,
                  const float* __restrict__ W_lin, const float* __restrict__ b_lin,
                  float* __restrict__ out)
{
    const int b   = blockIdx.x;
    const int tid = threadIdx.x;
    const int j   = tid >> 3;          // hidden index (0..50 for gate lanes)
    const int r   = tid & 3;           // gate role: 0=i 1=f 2=g 3=o
    const int h   = (tid >> 2) & 1;    // dot-product half
    const bool is_gate = (tid < 8 * HID);

    // h-vector slots: col<26 -> slot=col ; col>=26 -> slot=col+2 (16B-aligned halves)
    __shared__ __align__(16) float H0[2][56];
    __shared__ __align__(16) float H1[2][56];
    __shared__ float WS[8];
    __shared__ float XS[TLEN];

    if (tid < 56) { H0[0][tid] = 0.f; H0[1][tid] = 0.f; H1[0][tid] = 0.f; H1[1][tid] = 0.f; }
    if (tid < 8)  WS[tid] = 0.f;
    const float* xrow = x + (size_t)b * TLEN;
    for (int i = tid; i < TLEN; i += NTH) XS[i] = xrow[i];

    // per-lane weights: half h of rows (r*51+j) of W_hh0 / W_ih1 / W_hh1
    float w0[26], wi1[26], wh1[26];
    float bias0 = 0.f, bias1 = 0.f, wih0 = 0.f, wlinj = 0.f;
    const int grow = r * HID + j;
    if (is_gate) {
        #pragma unroll
        for (int k = 0; k < 26; ++k) {
            const int col = 26 * h + k;
            const bool v = (col < HID);
            w0[k]  = v ? W_hh0[grow * HID + col] : 0.f;
            wi1[k] = v ? W_ih1[grow * HID + col] : 0.f;
            wh1[k] = v ? W_hh1[grow * HID + col] : 0.f;
        }
        if (h == 0) {
            bias0 = b_ih0[grow] + b_hh0[grow];
            bias1 = b_ih1[grow] + b_hh1[grow];
            wih0  = W_ih0[grow];
        }
        if (r == 0 && h == 0) wlinj = W_lin[j];
    } else {
        #pragma unroll
        for (int k = 0; k < 26; ++k) { w0[k] = 0.f; wi1[k] = 0.f; wh1[k] = 0.f; }
    }
    const float blin = b_lin[0];
    const float am = (r == 2) ? 2.f : 1.f;     // tanh(a) = 2*sigm(2a) - 1
    const float ad = (r == 2) ? -1.f : 0.f;
    const int   slotj = j + ((j >= 26) ? 2 : 0);
    const int   hb    = 28 * h;

    float c0 = 0.f, c1 = 0.f;
    float* orow = out + (size_t)b * TLEN;
    __syncthreads();

    for (int t = 0; t < TLEN; ++t) {
        const int p = t & 1;

        // ---------- phase A : layer-0 ----------
        if (is_gate) {
            const float* hp = &H0[p][hb];
            float a0 = (h == 0) ? fmaf(XS[t], wih0, bias0) : 0.f;
            float a1 = 0.f;
            #pragma unroll
            for (int q = 0; q < 3; ++q) {
                float4 va = *reinterpret_cast<const float4*>(hp + 8 * q);
                float4 vb = *reinterpret_cast<const float4*>(hp + 8 * q + 4);
                a0 = fmaf(va.x, w0[8*q+0], a0); a0 = fmaf(va.y, w0[8*q+1], a0);
                a0 = fmaf(va.z, w0[8*q+2], a0); a0 = fmaf(va.w, w0[8*q+3], a0);
                a1 = fmaf(vb.x, w0[8*q+4], a1); a1 = fmaf(vb.y, w0[8*q+5], a1);
                a1 = fmaf(vb.z, w0[8*q+6], a1); a1 = fmaf(vb.w, w0[8*q+7], a1);
            }
            float2 tl = *reinterpret_cast<const float2*>(hp + 24);
            a0 = fmaf(tl.x, w0[24], a0);
            a1 = fmaf(tl.y, w0[25], a1);
            float acc = a0 + a1;
            acc += __shfl_xor(acc, 4, 64);                   // combine halves
            float act = fmaf(am, sigm(am * acc), ad);        // gate activation
            float x1 = __shfl_xor(act, 1, 64);
            float x2 = __shfl_xor(act, 2, 64);
            float x3 = __shfl_xor(act, 3, 64);
            float gi = (r==0)?act : (r==1)?x1  : (r==2)?x2  : x3;
            float gf = (r==0)?x1  : (r==1)?act : (r==2)?x3  : x2;
            float gg = (r==0)?x2  : (r==1)?x3  : (r==2)?act : x1;
            float go = (r==0)?x3  : (r==1)?x2  : (r==2)?x1  : act;
            c0 = fmaf(gf, c0, gi * gg);
            float th = fmaf(2.f, sigm(2.f * c0), -1.f);      // tanh(c0)
            float h0v = go * th;
            if ((tid & 7) == 0) H0[1 - p][slotj] = h0v;
        }
        __syncthreads();   // #1

        // ---------- phase B : layer-1 + projection ----------
        float part = 0.f;
        if (is_gate) {
            const float* h0n = &H0[1 - p][hb];
            const float* h1p = &H1[p][hb];
            float aA0 = (h == 0) ? bias1 : 0.f;
            float aA1 = 0.f, aB0 = 0.f, aB1 = 0.f;
            #pragma unroll
            for (int q = 0; q < 3; ++q) {
                float4 va = *reinterpret_cast<const float4*>(h0n + 8 * q);
                float4 vb = *reinterpret_cast<const float4*>(h0n + 8 * q + 4);
                float4 wa = *reinterpret_cast<const float4*>(h1p + 8 * q);
                float4 wb = *reinterpret_cast<const float4*>(h1p + 8 * q + 4);
                aA0 = fmaf(va.x, wi1[8*q+0], aA0); aA0 = fmaf(va.y, wi1[8*q+1], aA0);
                aA0 = fmaf(va.z, wi1[8*q+2], aA0); aA0 = fmaf(va.w, wi1[8*q+3], aA0);
                aA1 = fmaf(vb.x, wi1[8*q+4], aA1); aA1 = fmaf(vb.y, wi1[8*q+5], aA1);
                aA1 = fmaf(vb.z, wi1[8*q+6], aA1); aA1 = fmaf(vb.w, wi1[8*q+7], aA1);
                aB0 = fmaf(wa.x, wh1[8*q+0], aB0); aB0 = fmaf(wa.y, wh1[8*q+1], aB0);
                aB0 = fmaf(wa.z, wh1[8*q+2], aB0); aB0 = fmaf(wa.w, wh1[8*q+3], aB0);
                aB1 = fmaf(wb.x, wh1[8*q+4], aB1); aB1 = fmaf(wb.y, wh1[8*q+5], aB1);
                aB1 = fmaf(wb.z, wh1[8*q+6], aB1); aB1 = fmaf(wb.w, wh1[8*q+7], aB1);
            }
            float2 t0 = *reinterpret_cast<const float2*>(h0n + 24);
            float2 t1 = *reinterpret_cast<const float2*>(h1p + 24);
            aA0 = fmaf(t0.x, wi1[24], aA0);
            aA1 = fmaf(t0.y, wi1[25], aA1);
            aB0 = fmaf(t1.x, wh1[24], aB0);
            aB1 = fmaf(t1.y, wh1[25], aB1);
            float acc = (aA0 + aA1) + (aB0 + aB1);
            acc += __shfl_xor(acc, 4, 64);
            float act = fmaf(am, sigm(am * acc), ad);
            float x1 = __shfl_xor(act, 1, 64);
            float x2 = __shfl_xor(act, 2, 64);
            float x3 = __shfl_xor(act, 3, 64);
            float gi = (r==0)?act : (r==1)?x1  : (r==2)?x2  : x3;
            float gf = (r==0)?x1  : (r==1)?act : (r==2)?x3  : x2;
            float gg = (r==0)?x2  : (r==1)?x3  : (r==2)?act : x1;
            float go = (r==0)?x3  : (r==1)?x2  : (r==2)?x1  : act;
            c1 = fmaf(gf, c1, gi * gg);
            float th = fmaf(2.f, sigm(2.f * c1), -1.f);
            float h1v = go * th;
            if ((tid & 7) == 0) {
                H1[1 - p][slotj] = h1v;
                part = h1v * wlinj;
            }
        }
        // wave-level reduce of projection partials (partials sit at tid%8==0)
        part += __shfl_xor(part, 8, 64);
        part += __shfl_xor(part, 16, 64);
        part += __shfl_xor(part, 32, 64);
        if ((tid & 63) == 0) WS[tid >> 6] = part;
        __syncthreads();   // #2

        if (tid < 8) {
            float s = WS[tid];          // WS[7] stays 0
            s += __shfl_xor(s, 1, 64);
            s += __shfl_xor(s, 2, 64);
            s += __shfl_xor(s, 4, 64);
            if (tid == 0) orow[t] = s + blin;
        }
    }
}

extern "C" void kernel_launch(void* const* d_in, const int* in_sizes, int n_in,
                              void* d_out, int out_size, void* d_ws, size_t ws_size,
                              hipStream_t stream) {
    const float* x     = (const float*)d_in[0];
    const float* W_ih0 = (const float*)d_in[1];
    const float* W_hh0 = (const float*)d_in[2];
    const float* b_ih0 = (const float*)d_in[3];
    const float* b_hh0 = (const float*)d_in[4];
    const float* W_ih1 = (const float*)d_in[5];
    const float* W_hh1 = (const float*)d_in[6];
    const float* b_ih1 = (const float*)d_in[7];
    const float* b_hh1 = (const float*)d_in[8];
    const float* W_lin = (const float*)d_in[9];
    const float* b_lin = (const float*)d_in[10];
    float* out = (float*)d_out;

    const int B = in_sizes[0] / TLEN;
    lstm2_kernel<<<dim3(B), dim3(NTH), 0, stream>>>(
        x, W_ih0, W_hh0, b_ih0, b_hh0, W_ih1, W_hh1, b_ih1, b_hh1, W_lin, b_lin, out);
}